// Round 1
// 1137.704 us; speedup vs baseline: 1.0453x; 1.0453x over previous
//
#include <hip/hip_runtime.h>
#include <math.h>

// Problem constants (fixed by setup_inputs)
#define BATCH 32
#define TS    512     // Ts (phonemes / Tx)
#define TL    2048    // Tl (lip frames / Ty)
#define DD    256     // embedding dim
#define NEGV  -1e9f

// d_out sections (floats)
#define SIM_OFF   ((size_t)0)
#define GT_OFF    ((size_t)BATCH*TS*TL)            // 33,554,432
#define ALIGN_OFF ((size_t)2*BATCH*TS*TL)          // 67,108,864
#define DPRED_OFF ((size_t)3*BATCH*TS*TL)          // 100,663,296

// ---------------- ws layout (bytes) ----------------
#define WS_MEAN   0
#define WS_COF    256
#define WS_LSCALE 512
#define WS_TSCALE 262656
#define WS_BEGIN  328192
#define WS_END    393728
#define WS_START2 459264
#define WS_END2   524800
#define WS_DIRS   590848

// ============================================================
// Kernel 1: row norms -> scales.
// ============================================================
__global__ __launch_bounds__(256) void norm_kernel(const float* __restrict__ lip,
                                                   const float* __restrict__ phon,
                                                   float* __restrict__ lip_scale,
                                                   float* __restrict__ text_scale) {
    const int wave = threadIdx.x >> 6, lane = threadIdx.x & 63;
    const int row = blockIdx.x * 4 + wave;
    const int NL = BATCH * TL;
    const float* src = (row < NL) ? (lip + (size_t)row * DD)
                                  : (phon + (size_t)(row - NL) * DD);
    float4 q = *(const float4*)(src + lane * 4);
    float ss = q.x*q.x + q.y*q.y + q.z*q.z + q.w*q.w;
    #pragma unroll
    for (int off = 32; off; off >>= 1) ss += __shfl_xor(ss, off);
    if (lane == 0) {
        if (row < NL) lip_scale[row] = 1.0f / sqrtf(ss);
        else          text_scale[row - NL] = 1.0f / (sqrtf(ss) + 1.0f);
    }
}

// ============================================================
// Kernel 2: per-batch duration prep. One block (512 thr) per batch.
// ============================================================
__global__ __launch_bounds__(512) void prep_kernel(const int* __restrict__ d_targets,
                                                   const int* __restrict__ lip_lens,
                                                   int* __restrict__ begins,
                                                   int* __restrict__ ends,
                                                   float* __restrict__ cof_arr) {
    __shared__ int   si[512];
    __shared__ float sf[512];
    __shared__ int   sx[512];
    const int b = blockIdx.x, t = threadIdx.x;
    const int d = d_targets[b * TS + t];
    const int lipL = lip_lens[b];

    si[t] = d; __syncthreads();
    for (int off = 256; off; off >>= 1) { if (t < off) si[t] += si[t + off]; __syncthreads(); }
    const int sum_d = si[0]; __syncthreads();

    const float cofv = (float)sum_d / (float)lipL;
    float lt = rintf((float)d / cofv);

    sf[t] = lt; __syncthreads();
    for (int off = 256; off; off >>= 1) { if (t < off) sf[t] += sf[t + off]; __syncthreads(); }
    const float sumlt = sf[0]; __syncthreads();
    const float dif = (float)lipL - sumlt;

    sf[t] = lt; sx[t] = t; __syncthreads();
    for (int off = 256; off; off >>= 1) {
        if (t < off) {
            float v2 = sf[t + off]; int i2 = sx[t + off];
            if (v2 > sf[t] || (v2 == sf[t] && i2 < sx[t])) { sf[t] = v2; sx[t] = i2; }
        }
        __syncthreads();
    }
    const int max_idx = sx[0]; __syncthreads();
    if (t == max_idx) lt += dif;
    const int li = (int)lt;

    si[t] = li; __syncthreads();
    for (int off = 1; off < 512; off <<= 1) {
        int add = (t >= off) ? si[t - off] : 0;
        __syncthreads();
        si[t] += add;
        __syncthreads();
    }
    const int e = si[t];
    begins[b * TS + t] = e - li;
    ends[b * TS + t]   = e;
    if (t == 0) cof_arr[b] = cofv;
}

// ============================================================
// Kernel 3: batched fp32 GEMM  sim[b][s][l] = sum_d textN[s][d]*lipN[l][d]
// 128x128 tile, BK=16, 256 threads, 8x8 micro-tile (4+4 split).
// gt_similarity fused into epilogue. NEW: also writes a transposed
// copy simT[b][l][s] (into the alignment out-section, used as
// scratch) so the DP kernel gets coalesced j-major loads.
// ============================================================
__global__ __launch_bounds__(256) void gemm_kernel(const float* __restrict__ lip,
                                                   const float* __restrict__ phon,
                                                   const float* __restrict__ lip_scale,
                                                   const float* __restrict__ text_scale,
                                                   const int* __restrict__ begins,
                                                   const int* __restrict__ ends,
                                                   float* __restrict__ sim,
                                                   float* __restrict__ gt,
                                                   float* __restrict__ simT) {
    const int b = blockIdx.z, tm = blockIdx.y, tn = blockIdx.x;
    const int t = threadIdx.x;
    __shared__ __align__(16) float As[16][132];
    __shared__ __align__(16) float Bs[16][132];

    const int r = t >> 1, sub = t & 1;
    const int tx = t & 15, ty = t >> 4;

    const float* Ag = phon + ((size_t)(b * TS + tm * 128 + r)) * DD + sub * 8;
    const float* Bg = lip  + ((size_t)(b * TL + tn * 128 + r)) * DD + sub * 8;
    const float sA = text_scale[b * TS + tm * 128 + r];
    const float sB = lip_scale[b * TL + tn * 128 + r];

    float4 ra0 = *(const float4*)(Ag);
    float4 ra1 = *(const float4*)(Ag + 4);
    float4 rb0 = *(const float4*)(Bg);
    float4 rb1 = *(const float4*)(Bg + 4);

    float acc[8][8];
    #pragma unroll
    for (int i = 0; i < 8; ++i)
        #pragma unroll
        for (int j = 0; j < 8; ++j) acc[i][j] = 0.0f;

    for (int kt = 0; kt < 16; ++kt) {
        __syncthreads();
        {
            const float* pa0 = &ra0.x; const float* pa1 = &ra1.x;
            const float* pb0 = &rb0.x; const float* pb1 = &rb1.x;
            #pragma unroll
            for (int kk = 0; kk < 4; ++kk) {
                As[sub * 8 + kk][r]     = pa0[kk] * sA;
                As[sub * 8 + 4 + kk][r] = pa1[kk] * sA;
                Bs[sub * 8 + kk][r]     = pb0[kk] * sB;
                Bs[sub * 8 + 4 + kk][r] = pb1[kk] * sB;
            }
        }
        __syncthreads();
        if (kt < 15) {
            ra0 = *(const float4*)(Ag + (kt + 1) * 16);
            ra1 = *(const float4*)(Ag + (kt + 1) * 16 + 4);
            rb0 = *(const float4*)(Bg + (kt + 1) * 16);
            rb1 = *(const float4*)(Bg + (kt + 1) * 16 + 4);
        }
        #pragma unroll
        for (int kk = 0; kk < 16; ++kk) {
            float4 t0 = *(const float4*)&As[kk][ty * 4];
            float4 t1 = *(const float4*)&As[kk][64 + ty * 4];
            float4 t2 = *(const float4*)&Bs[kk][tx * 4];
            float4 t3 = *(const float4*)&Bs[kk][64 + tx * 4];
            float a[8] = {t0.x, t0.y, t0.z, t0.w, t1.x, t1.y, t1.z, t1.w};
            float bb[8] = {t2.x, t2.y, t2.z, t2.w, t3.x, t3.y, t3.z, t3.w};
            #pragma unroll
            for (int i = 0; i < 8; ++i)
                #pragma unroll
                for (int j = 0; j < 8; ++j)
                    acc[i][j] = fmaf(a[i], bb[j], acc[i][j]);
        }
    }

    // epilogue: similarity + gt_similarity (x-major)
    const size_t base = (size_t)b * TS * TL;
    #pragma unroll
    for (int mi = 0; mi < 2; ++mi) {
        #pragma unroll
        for (int im = 0; im < 4; ++im) {
            const int srow = tm * 128 + mi * 64 + ty * 4 + im;
            const int ai = mi * 4 + im;
            float* prow = sim + base + (size_t)srow * TL + tn * 128;
            float4 w0 = {acc[ai][0], acc[ai][1], acc[ai][2], acc[ai][3]};
            float4 w1 = {acc[ai][4], acc[ai][5], acc[ai][6], acc[ai][7]};
            *(float4*)(prow + tx * 4) = w0;
            *(float4*)(prow + 64 + tx * 4) = w1;

            const int bg = begins[b * TS + srow], en = ends[b * TS + srow];
            const int l0 = tn * 128 + tx * 4;
            float4 g0, g1;
            g0.x = (l0 + 0 >= bg && l0 + 0 < en) ? 1.f : 0.f;
            g0.y = (l0 + 1 >= bg && l0 + 1 < en) ? 1.f : 0.f;
            g0.z = (l0 + 2 >= bg && l0 + 2 < en) ? 1.f : 0.f;
            g0.w = (l0 + 3 >= bg && l0 + 3 < en) ? 1.f : 0.f;
            g1.x = (l0 + 64 >= bg && l0 + 64 < en) ? 1.f : 0.f;
            g1.y = (l0 + 65 >= bg && l0 + 65 < en) ? 1.f : 0.f;
            g1.z = (l0 + 66 >= bg && l0 + 66 < en) ? 1.f : 0.f;
            g1.w = (l0 + 67 >= bg && l0 + 67 < en) ? 1.f : 0.f;
            float* grow = gt + base + (size_t)srow * TL + tn * 128;
            *(float4*)(grow + tx * 4) = g0;
            *(float4*)(grow + 64 + tx * 4) = g1;
        }
    }

    // NEW epilogue: transposed copy simT[b][l][s]  (row stride TS floats)
    // Thread's l-cols: tn*128 + {tx*4+c, 64+tx*4+c}, c=0..3.
    // Thread's s-rows: tm*128 + {ty*4..ty*4+3, 64+ty*4..64+ty*4+3}.
    // Per store instr, the 4 ty-lanes of a wave cover 64B contiguous of one l-row.
    {
        float* tb = simT + (size_t)b * TL * TS + (size_t)(tn * 128) * TS + tm * 128;
        #pragma unroll
        for (int bj = 0; bj < 8; ++bj) {
            const int lloc = (bj < 4) ? (tx * 4 + bj) : (64 + tx * 4 + (bj - 4));
            float* trow = tb + (size_t)lloc * TS;
            float4 w0 = {acc[0][bj], acc[1][bj], acc[2][bj], acc[3][bj]};
            float4 w1 = {acc[4][bj], acc[5][bj], acc[6][bj], acc[7][bj]};
            *(float4*)(trow + ty * 4) = w0;
            *(float4*)(trow + 64 + ty * 4) = w1;
        }
    }
}

// ============================================================
// Kernel 4: maximum_path DP. One wave per batch; lane L owns
// x = 8L..8L+7. NOW reads j-major simT: per step one contiguous
// 2KB row, lane L takes floats [8L, 8L+8) -> fully coalesced.
// Stay bits packed MSB-first (w = 2w + stay) into per-x 32-bit
// words so the backtrack can skip stay-runs with ctz.
// ============================================================
__device__ __forceinline__ void load8T(float4 (&buf)[8][2], const float* simTb, int L, int jb) {
    #pragma unroll
    for (int s = 0; s < 8; ++s) {
        const float* p = simTb + (size_t)(jb + s) * TS + L * 8;
        buf[s][0] = *(const float4*)p;
        buf[s][1] = *(const float4*)(p + 4);
    }
}

template <bool CHK>
__device__ __forceinline__ void step8T(float4 (&buf)[8][2], int jb, float (&v)[8],
                                       unsigned (&w)[8], const float (&xm)[8], int L) {
    #pragma unroll
    for (int s = 0; s < 8; ++s) {
        const int j = jb + s;
        float up = __shfl_up(v[7], 1);
        if (L == 0) up = NEGV;
        const float* vals = (const float*)&buf[s][0];
        #pragma unroll
        for (int i = 7; i >= 0; --i) {
            const float v0 = (i == 0) ? up : v[i - 1];
            const unsigned stay = (v[i] >= v0) ? 1u : 0u;
            const float vm = fmaxf(v[i], v0);
            float nv = fmaf(vals[i], xm[i], vm);     // masked value add
            if (CHK) nv = ((L * 8 + i) <= j) ? nv : NEGV;
            w[i] = w[i] * 2u + stay;
            v[i] = nv;
        }
    }
}

__global__ __launch_bounds__(64) void dp_kernel(const float* __restrict__ simT,
                                                const int* __restrict__ src_lens,
                                                const int* __restrict__ lip_lens,
                                                const float* __restrict__ cof_arr,
                                                float* __restrict__ mean_out,
                                                unsigned* __restrict__ dirs,
                                                int* __restrict__ start2,
                                                int* __restrict__ end2) {
    const int b = blockIdx.x, L = threadIdx.x;
    if (b == 0 && L == 0) {
        float s = 0.f;
        for (int i = 0; i < BATCH; ++i) s += cof_arr[i];
        mean_out[0] = s / 32.0f;
    }
    const int srcL = src_lens[b], lipL = lip_lens[b];
    const float* simTb = simT + (size_t)b * TL * TS;

    float v[8]; unsigned w[8]; float xm[8];
    #pragma unroll
    for (int i = 0; i < 8; ++i) {
        v[i] = 0.f; w[i] = 0u;
        xm[i] = (L * 8 + i < srcL) ? 1.f : 0.f;
    }
    float4 bufA[8][2], bufB[8][2];
    const int jmax = (lipL + 31) & ~31;   // multiple of 32 (and of 16)

    load8T(bufA, simTb, L, 0);
    for (int jb = 0; jb < jmax; jb += 16) {
        load8T(bufB, simTb, L, jb + 8);
        if (jb < 512) step8T<true>(bufA, jb, v, w, xm, L);
        else          step8T<false>(bufA, jb, v, w, xm, L);
        if ((jb & 31) == 24) {
            #pragma unroll
            for (int i = 0; i < 8; ++i) {
                dirs[((size_t)b * TS + L * 8 + i) * 64 + (jb >> 5)] = w[i];
                w[i] = 0u;
            }
        }
        if (jb + 16 < jmax) load8T(bufA, simTb, L, jb + 16);
        if (jb + 8 < 512) step8T<true>(bufB, jb + 8, v, w, xm, L);
        else              step8T<false>(bufB, jb + 8, v, w, xm, L);
        if (((jb + 8) & 31) == 24) {
            #pragma unroll
            for (int i = 0; i < 8; ++i) {
                dirs[((size_t)b * TS + L * 8 + i) * 64 + ((jb + 8) >> 5)] = w[i];
                w[i] = 0u;
            }
        }
    }

    // ---- backtrack (wave-uniform) ----
    #pragma unroll
    for (int i = 0; i < 8; ++i) {
        start2[b * TS + L + i * 64] = 0;
        end2[b * TS + L + i * 64] = 0;
    }
    asm volatile("s_waitcnt vmcnt(0)" ::: "memory");  // zeros & dirs flushed before chain

    int x = srcL - 1;
    if (L == 0) end2[b * TS + x] = lipL;
    int j = lipL - 1;
    while (x > 0 && j >= 0) {
        const unsigned W = dirs[((size_t)b * TS + x) * 64 + (j >> 5)];
        const int jj = j & 31;
        const unsigned m = (~W) & (0xFFFFFFFFu << (31 - jj));
        if (m == 0u) { j -= jj + 1; continue; }
        const int jp = __builtin_ctz(m);
        const int jprime = (j & ~31) + (31 - jp);
        if (L == 0) { start2[b * TS + x] = jprime; end2[b * TS + x - 1] = jprime; }
        x -= 1; j = jprime - 1;
    }
}

// ============================================================
// Kernel 5: alignment rows (run indicators) + d_predictions
// NOTE: fully overwrites the align section (which dp used as simT
// scratch) — every element written.
// ============================================================
__global__ __launch_bounds__(256) void align_kernel(const int* __restrict__ start2,
                                                    const int* __restrict__ end2,
                                                    const float* __restrict__ mean_cof,
                                                    float* __restrict__ alignOut,
                                                    float* __restrict__ dpred) {
    const int s = blockIdx.x, b = blockIdx.y, t = threadIdx.x;
    const int st = start2[b * TS + s], en = end2[b * TS + s];
    float* row = alignOut + ((size_t)b * TS + s) * TL;
    const int l0 = t * 8;
    float4 r0, r1;
    r0.x = (l0 + 0 >= st && l0 + 0 < en) ? 1.f : 0.f;
    r0.y = (l0 + 1 >= st && l0 + 1 < en) ? 1.f : 0.f;
    r0.z = (l0 + 2 >= st && l0 + 2 < en) ? 1.f : 0.f;
    r0.w = (l0 + 3 >= st && l0 + 3 < en) ? 1.f : 0.f;
    r1.x = (l0 + 4 >= st && l0 + 4 < en) ? 1.f : 0.f;
    r1.y = (l0 + 5 >= st && l0 + 5 < en) ? 1.f : 0.f;
    r1.z = (l0 + 6 >= st && l0 + 6 < en) ? 1.f : 0.f;
    r1.w = (l0 + 7 >= st && l0 + 7 < en) ? 1.f : 0.f;
    *(float4*)(row + l0) = r0;
    *(float4*)(row + l0 + 4) = r1;
    if (t == 0) dpred[b * TS + s] = (float)(en - st) * mean_cof[0];
}

// ============================================================
extern "C" void kernel_launch(void* const* d_in, const int* in_sizes, int n_in,
                              void* d_out, int out_size, void* d_ws, size_t ws_size,
                              hipStream_t stream) {
    const float* lip   = (const float*)d_in[0];   // [B, Tl, D]
    const float* phon  = (const float*)d_in[1];   // [B, Ts, D]
    const int* d_tg    = (const int*)d_in[2];     // [B, Ts]
    const int* src_l   = (const int*)d_in[3];     // [B]
    const int* lip_l   = (const int*)d_in[4];     // [B]
    float* out = (float*)d_out;

    char* ws = (char*)d_ws;
    float*    mean_cof   = (float*)(ws + WS_MEAN);
    float*    cof_arr    = (float*)(ws + WS_COF);
    float*    lip_scale  = (float*)(ws + WS_LSCALE);
    float*    text_scale = (float*)(ws + WS_TSCALE);
    int*      begins     = (int*)(ws + WS_BEGIN);
    int*      ends       = (int*)(ws + WS_END);
    int*      start2     = (int*)(ws + WS_START2);
    int*      end2       = (int*)(ws + WS_END2);
    unsigned* dirs       = (unsigned*)(ws + WS_DIRS);

    float* sim   = out + SIM_OFF;
    float* gt    = out + GT_OFF;
    float* aln   = out + ALIGN_OFF;   // doubles as simT scratch before align_kernel
    float* dpred = out + DPRED_OFF;

    norm_kernel<<<(BATCH * TL + BATCH * TS) / 4, 256, 0, stream>>>(lip, phon, lip_scale, text_scale);
    prep_kernel<<<BATCH, 512, 0, stream>>>(d_tg, lip_l, begins, ends, cof_arr);
    gemm_kernel<<<dim3(TL / 128, TS / 128, BATCH), 256, 0, stream>>>(lip, phon, lip_scale, text_scale,
                                                                     begins, ends, sim, gt, aln);
    dp_kernel<<<BATCH, 64, 0, stream>>>(aln, src_l, lip_l, cof_arr, mean_cof, dirs, start2, end2);
    align_kernel<<<dim3(TS, BATCH), 256, 0, stream>>>(start2, end2, mean_cof, aln, dpred);
}

// Round 2
// 1010.608 us; speedup vs baseline: 1.1768x; 1.1258x over previous
//
#include <hip/hip_runtime.h>
#include <math.h>

// Problem constants (fixed by setup_inputs)
#define BATCH 32
#define TS    512     // Ts (phonemes / Tx)
#define TL    2048    // Tl (lip frames / Ty)
#define DD    256     // embedding dim
#define NEGV  -1e9f

// d_out sections (floats)
#define SIM_OFF   ((size_t)0)
#define GT_OFF    ((size_t)BATCH*TS*TL)            // 33,554,432
#define ALIGN_OFF ((size_t)2*BATCH*TS*TL)          // 67,108,864
#define DPRED_OFF ((size_t)3*BATCH*TS*TL)          // 100,663,296

// ---------------- ws layout (bytes) ----------------
#define WS_MEAN   0
#define WS_COF    256
#define WS_LSCALE 512
#define WS_TSCALE 262656
#define WS_BEGIN  328192
#define WS_END    393728
#define WS_START2 459264
#define WS_END2   524800

// ============================================================
// Kernel 1: row norms -> scales.
// ============================================================
__global__ __launch_bounds__(256) void norm_kernel(const float* __restrict__ lip,
                                                   const float* __restrict__ phon,
                                                   float* __restrict__ lip_scale,
                                                   float* __restrict__ text_scale) {
    const int wave = threadIdx.x >> 6, lane = threadIdx.x & 63;
    const int row = blockIdx.x * 4 + wave;
    const int NL = BATCH * TL;
    const float* src = (row < NL) ? (lip + (size_t)row * DD)
                                  : (phon + (size_t)(row - NL) * DD);
    float4 q = *(const float4*)(src + lane * 4);
    float ss = q.x*q.x + q.y*q.y + q.z*q.z + q.w*q.w;
    #pragma unroll
    for (int off = 32; off; off >>= 1) ss += __shfl_xor(ss, off);
    if (lane == 0) {
        if (row < NL) lip_scale[row] = 1.0f / sqrtf(ss);
        else          text_scale[row - NL] = 1.0f / (sqrtf(ss) + 1.0f);
    }
}

// ============================================================
// Kernel 2: per-batch duration prep. One block (512 thr) per batch.
// ============================================================
__global__ __launch_bounds__(512) void prep_kernel(const int* __restrict__ d_targets,
                                                   const int* __restrict__ lip_lens,
                                                   int* __restrict__ begins,
                                                   int* __restrict__ ends,
                                                   float* __restrict__ cof_arr) {
    __shared__ int   si[512];
    __shared__ float sf[512];
    __shared__ int   sx[512];
    const int b = blockIdx.x, t = threadIdx.x;
    const int d = d_targets[b * TS + t];
    const int lipL = lip_lens[b];

    si[t] = d; __syncthreads();
    for (int off = 256; off; off >>= 1) { if (t < off) si[t] += si[t + off]; __syncthreads(); }
    const int sum_d = si[0]; __syncthreads();

    const float cofv = (float)sum_d / (float)lipL;
    float lt = rintf((float)d / cofv);

    sf[t] = lt; __syncthreads();
    for (int off = 256; off; off >>= 1) { if (t < off) sf[t] += sf[t + off]; __syncthreads(); }
    const float sumlt = sf[0]; __syncthreads();
    const float dif = (float)lipL - sumlt;

    sf[t] = lt; sx[t] = t; __syncthreads();
    for (int off = 256; off; off >>= 1) {
        if (t < off) {
            float v2 = sf[t + off]; int i2 = sx[t + off];
            if (v2 > sf[t] || (v2 == sf[t] && i2 < sx[t])) { sf[t] = v2; sx[t] = i2; }
        }
        __syncthreads();
    }
    const int max_idx = sx[0]; __syncthreads();
    if (t == max_idx) lt += dif;
    const int li = (int)lt;

    si[t] = li; __syncthreads();
    for (int off = 1; off < 512; off <<= 1) {
        int add = (t >= off) ? si[t - off] : 0;
        __syncthreads();
        si[t] += add;
        __syncthreads();
    }
    const int e = si[t];
    begins[b * TS + t] = e - li;
    ends[b * TS + t]   = e;
    if (t == 0) cof_arr[b] = cofv;
}

// ============================================================
// Kernel 3: batched fp32 GEMM  sim[b][s][l] = sum_d textN[s][d]*lipN[l][d]
// 128x128 tile, BK=16, 256 threads, 8x8 micro-tile (4+4 split).
// gt_similarity fused into epilogue. Also writes a transposed
// copy simT[b][l][s] (into the alignment out-section, used as
// scratch) so the DP kernel gets coalesced j-major loads.
// ============================================================
__global__ __launch_bounds__(256) void gemm_kernel(const float* __restrict__ lip,
                                                   const float* __restrict__ phon,
                                                   const float* __restrict__ lip_scale,
                                                   const float* __restrict__ text_scale,
                                                   const int* __restrict__ begins,
                                                   const int* __restrict__ ends,
                                                   float* __restrict__ sim,
                                                   float* __restrict__ gt,
                                                   float* __restrict__ simT) {
    const int b = blockIdx.z, tm = blockIdx.y, tn = blockIdx.x;
    const int t = threadIdx.x;
    __shared__ __align__(16) float As[16][132];
    __shared__ __align__(16) float Bs[16][132];

    const int r = t >> 1, sub = t & 1;
    const int tx = t & 15, ty = t >> 4;

    const float* Ag = phon + ((size_t)(b * TS + tm * 128 + r)) * DD + sub * 8;
    const float* Bg = lip  + ((size_t)(b * TL + tn * 128 + r)) * DD + sub * 8;
    const float sA = text_scale[b * TS + tm * 128 + r];
    const float sB = lip_scale[b * TL + tn * 128 + r];

    float4 ra0 = *(const float4*)(Ag);
    float4 ra1 = *(const float4*)(Ag + 4);
    float4 rb0 = *(const float4*)(Bg);
    float4 rb1 = *(const float4*)(Bg + 4);

    float acc[8][8];
    #pragma unroll
    for (int i = 0; i < 8; ++i)
        #pragma unroll
        for (int j = 0; j < 8; ++j) acc[i][j] = 0.0f;

    for (int kt = 0; kt < 16; ++kt) {
        __syncthreads();
        {
            const float* pa0 = &ra0.x; const float* pa1 = &ra1.x;
            const float* pb0 = &rb0.x; const float* pb1 = &rb1.x;
            #pragma unroll
            for (int kk = 0; kk < 4; ++kk) {
                As[sub * 8 + kk][r]     = pa0[kk] * sA;
                As[sub * 8 + 4 + kk][r] = pa1[kk] * sA;
                Bs[sub * 8 + kk][r]     = pb0[kk] * sB;
                Bs[sub * 8 + 4 + kk][r] = pb1[kk] * sB;
            }
        }
        __syncthreads();
        if (kt < 15) {
            ra0 = *(const float4*)(Ag + (kt + 1) * 16);
            ra1 = *(const float4*)(Ag + (kt + 1) * 16 + 4);
            rb0 = *(const float4*)(Bg + (kt + 1) * 16);
            rb1 = *(const float4*)(Bg + (kt + 1) * 16 + 4);
        }
        #pragma unroll
        for (int kk = 0; kk < 16; ++kk) {
            float4 t0 = *(const float4*)&As[kk][ty * 4];
            float4 t1 = *(const float4*)&As[kk][64 + ty * 4];
            float4 t2 = *(const float4*)&Bs[kk][tx * 4];
            float4 t3 = *(const float4*)&Bs[kk][64 + tx * 4];
            float a[8] = {t0.x, t0.y, t0.z, t0.w, t1.x, t1.y, t1.z, t1.w};
            float bb[8] = {t2.x, t2.y, t2.z, t2.w, t3.x, t3.y, t3.z, t3.w};
            #pragma unroll
            for (int i = 0; i < 8; ++i)
                #pragma unroll
                for (int j = 0; j < 8; ++j)
                    acc[i][j] = fmaf(a[i], bb[j], acc[i][j]);
        }
    }

    // epilogue: similarity + gt_similarity (x-major)
    const size_t base = (size_t)b * TS * TL;
    #pragma unroll
    for (int mi = 0; mi < 2; ++mi) {
        #pragma unroll
        for (int im = 0; im < 4; ++im) {
            const int srow = tm * 128 + mi * 64 + ty * 4 + im;
            const int ai = mi * 4 + im;
            float* prow = sim + base + (size_t)srow * TL + tn * 128;
            float4 w0 = {acc[ai][0], acc[ai][1], acc[ai][2], acc[ai][3]};
            float4 w1 = {acc[ai][4], acc[ai][5], acc[ai][6], acc[ai][7]};
            *(float4*)(prow + tx * 4) = w0;
            *(float4*)(prow + 64 + tx * 4) = w1;

            const int bg = begins[b * TS + srow], en = ends[b * TS + srow];
            const int l0 = tn * 128 + tx * 4;
            float4 g0, g1;
            g0.x = (l0 + 0 >= bg && l0 + 0 < en) ? 1.f : 0.f;
            g0.y = (l0 + 1 >= bg && l0 + 1 < en) ? 1.f : 0.f;
            g0.z = (l0 + 2 >= bg && l0 + 2 < en) ? 1.f : 0.f;
            g0.w = (l0 + 3 >= bg && l0 + 3 < en) ? 1.f : 0.f;
            g1.x = (l0 + 64 >= bg && l0 + 64 < en) ? 1.f : 0.f;
            g1.y = (l0 + 65 >= bg && l0 + 65 < en) ? 1.f : 0.f;
            g1.z = (l0 + 66 >= bg && l0 + 66 < en) ? 1.f : 0.f;
            g1.w = (l0 + 67 >= bg && l0 + 67 < en) ? 1.f : 0.f;
            float* grow = gt + base + (size_t)srow * TL + tn * 128;
            *(float4*)(grow + tx * 4) = g0;
            *(float4*)(grow + 64 + tx * 4) = g1;
        }
    }

    // transposed copy simT[b][l][s]  (row stride TS floats)
    {
        float* tb = simT + (size_t)b * TL * TS + (size_t)(tn * 128) * TS + tm * 128;
        #pragma unroll
        for (int bj = 0; bj < 8; ++bj) {
            const int lloc = (bj < 4) ? (tx * 4 + bj) : (64 + tx * 4 + (bj - 4));
            float* trow = tb + (size_t)lloc * TS;
            float4 w0 = {acc[0][bj], acc[1][bj], acc[2][bj], acc[3][bj]};
            float4 w1 = {acc[4][bj], acc[5][bj], acc[6][bj], acc[7][bj]};
            *(float4*)(trow + ty * 4) = w0;
            *(float4*)(trow + 64 + ty * 4) = w1;
        }
    }
}

// ============================================================
// Kernel 4: maximum_path DP. One wave per batch; lane L owns
// x = 8L..8L+7. Reads j-major simT (coalesced). Triple-buffered
// register prefetch (3 x 8-step chunks = 192 VGPR) with
// __launch_bounds__(64,1) so NOTHING spills (prev version's 120
// VGPR cap spilled the buffers to scratch -> 600 cyc/step).
// Stay bits packed MSB-first into per-x 32-bit words held in LDS
// (128 KB) so forward-pass flushes are ds_write and the serial
// backtrack chain is LDS-latency, not L2-latency.
// ============================================================
__device__ __forceinline__ void load8T(float4 (&buf)[8][2], const float* simTb, int L, int jb) {
    #pragma unroll
    for (int s = 0; s < 8; ++s) {
        const float* p = simTb + (size_t)(jb + s) * TS + L * 8;
        buf[s][0] = *(const float4*)p;
        buf[s][1] = *(const float4*)(p + 4);
    }
}

template <bool CHK>
__device__ __forceinline__ void step8T(float4 (&buf)[8][2], int jb, float (&v)[8],
                                       unsigned (&w)[8], const float (&xm)[8], int L) {
    #pragma unroll
    for (int s = 0; s < 8; ++s) {
        const int j = jb + s;
        float up = __shfl_up(v[7], 1);
        if (L == 0) up = NEGV;
        const float* vals = (const float*)&buf[s][0];
        #pragma unroll
        for (int i = 7; i >= 0; --i) {
            const float v0 = (i == 0) ? up : v[i - 1];
            const unsigned stay = (v[i] >= v0) ? 1u : 0u;
            const float vm = fmaxf(v[i], v0);
            float nv = fmaf(vals[i], xm[i], vm);     // masked value add
            if (CHK) nv = ((L * 8 + i) <= j) ? nv : NEGV;
            w[i] = w[i] * 2u + stay;
            v[i] = nv;
        }
    }
}

__global__ __launch_bounds__(64, 1) void dp_kernel(const float* __restrict__ simT,
                                                   const int* __restrict__ src_lens,
                                                   const int* __restrict__ lip_lens,
                                                   const float* __restrict__ cof_arr,
                                                   float* __restrict__ mean_out,
                                                   int* __restrict__ start2,
                                                   int* __restrict__ end2) {
    // dirs bit-matrix in LDS: [word][x] -> 64 * 512 u32 = 128 KB
    __shared__ unsigned dirs_lds[64 * 512];

    const int b = blockIdx.x, L = threadIdx.x;
    if (b == 0 && L == 0) {
        float s = 0.f;
        for (int i = 0; i < BATCH; ++i) s += cof_arr[i];
        mean_out[0] = s / 32.0f;
    }
    const int srcL = src_lens[b], lipL = lip_lens[b];
    const float* simTb = simT + (size_t)b * TL * TS;

    float v[8]; unsigned w[8]; float xm[8];
    #pragma unroll
    for (int i = 0; i < 8; ++i) {
        v[i] = 0.f; w[i] = 0u;
        xm[i] = (L * 8 + i < srcL) ? 1.f : 0.f;
    }
    float4 bufA[8][2], bufB[8][2], bufC[8][2];
    const int jmax = (lipL + 31) & ~31;   // multiple of 32; >= 1024

    load8T(bufA, simTb, L, 0);
    load8T(bufB, simTb, L, 8);
    load8T(bufC, simTb, L, 16);

    int jb = 0;
    // one chunk = 8 steps; compute chunk n, then prefetch chunk n+3
#define DP_CHUNK(BUF)                                                          \
    do {                                                                       \
        if (jb < 512) step8T<true>(BUF, jb, v, w, xm, L);                      \
        else          step8T<false>(BUF, jb, v, w, xm, L);                     \
        if ((jb & 31) == 24) {                                                 \
            const int wd = jb >> 5;                                            \
            _Pragma("unroll")                                                  \
            for (int i = 0; i < 8; ++i) {                                      \
                dirs_lds[wd * 512 + L * 8 + i] = w[i];                         \
                w[i] = 0u;                                                     \
            }                                                                  \
        }                                                                      \
        {                                                                      \
            int jl = jb + 24;                                                  \
            if (jl > TL - 8) jl = TL - 8;   /* clamp: stay in-bounds */        \
            load8T(BUF, simTb, L, jl);                                         \
        }                                                                      \
        jb += 8;                                                               \
    } while (0)

    while (jb < jmax) {
        DP_CHUNK(bufA);
        if (jb >= jmax) break;
        DP_CHUNK(bufB);
        if (jb >= jmax) break;
        DP_CHUNK(bufC);
    }
#undef DP_CHUNK

    // ---- backtrack (wave-uniform; dirs in LDS) ----
    #pragma unroll
    for (int i = 0; i < 8; ++i) {
        start2[b * TS + L + i * 64] = 0;
        end2[b * TS + L + i * 64] = 0;
    }
    asm volatile("s_waitcnt vmcnt(0)" ::: "memory");  // zeros flushed before chain stores

    int x = srcL - 1;
    if (L == 0) end2[b * TS + x] = lipL;
    int j = lipL - 1;
    while (x > 0 && j >= 0) {
        const unsigned W = dirs_lds[(j >> 5) * 512 + x];
        const int jj = j & 31;
        const unsigned m = (~W) & (0xFFFFFFFFu << (31 - jj)); // moves at j' <= j in this word
        if (m == 0u) { j -= jj + 1; continue; }               // whole span stays
        const int jp = __builtin_ctz(m);
        const int jprime = (j & ~31) + (31 - jp);
        if (L == 0) { start2[b * TS + x] = jprime; end2[b * TS + x - 1] = jprime; }
        x -= 1; j = jprime - 1;
    }
    // start2[b][0] stays 0 (pre-zeroed), matching the path reaching x=0 at j=0
}

// ============================================================
// Kernel 5: alignment rows (run indicators) + d_predictions
// Fully overwrites the align section (which dp used as simT scratch).
// ============================================================
__global__ __launch_bounds__(256) void align_kernel(const int* __restrict__ start2,
                                                    const int* __restrict__ end2,
                                                    const float* __restrict__ mean_cof,
                                                    float* __restrict__ alignOut,
                                                    float* __restrict__ dpred) {
    const int s = blockIdx.x, b = blockIdx.y, t = threadIdx.x;
    const int st = start2[b * TS + s], en = end2[b * TS + s];
    float* row = alignOut + ((size_t)b * TS + s) * TL;
    const int l0 = t * 8;
    float4 r0, r1;
    r0.x = (l0 + 0 >= st && l0 + 0 < en) ? 1.f : 0.f;
    r0.y = (l0 + 1 >= st && l0 + 1 < en) ? 1.f : 0.f;
    r0.z = (l0 + 2 >= st && l0 + 2 < en) ? 1.f : 0.f;
    r0.w = (l0 + 3 >= st && l0 + 3 < en) ? 1.f : 0.f;
    r1.x = (l0 + 4 >= st && l0 + 4 < en) ? 1.f : 0.f;
    r1.y = (l0 + 5 >= st && l0 + 5 < en) ? 1.f : 0.f;
    r1.z = (l0 + 6 >= st && l0 + 6 < en) ? 1.f : 0.f;
    r1.w = (l0 + 7 >= st && l0 + 7 < en) ? 1.f : 0.f;
    *(float4*)(row + l0) = r0;
    *(float4*)(row + l0 + 4) = r1;
    if (t == 0) dpred[b * TS + s] = (float)(en - st) * mean_cof[0];
}

// ============================================================
extern "C" void kernel_launch(void* const* d_in, const int* in_sizes, int n_in,
                              void* d_out, int out_size, void* d_ws, size_t ws_size,
                              hipStream_t stream) {
    const float* lip   = (const float*)d_in[0];   // [B, Tl, D]
    const float* phon  = (const float*)d_in[1];   // [B, Ts, D]
    const int* d_tg    = (const int*)d_in[2];     // [B, Ts]
    const int* src_l   = (const int*)d_in[3];     // [B]
    const int* lip_l   = (const int*)d_in[4];     // [B]
    float* out = (float*)d_out;

    char* ws = (char*)d_ws;
    float*    mean_cof   = (float*)(ws + WS_MEAN);
    float*    cof_arr    = (float*)(ws + WS_COF);
    float*    lip_scale  = (float*)(ws + WS_LSCALE);
    float*    text_scale = (float*)(ws + WS_TSCALE);
    int*      begins     = (int*)(ws + WS_BEGIN);
    int*      ends       = (int*)(ws + WS_END);
    int*      start2     = (int*)(ws + WS_START2);
    int*      end2       = (int*)(ws + WS_END2);

    float* sim   = out + SIM_OFF;
    float* gt    = out + GT_OFF;
    float* aln   = out + ALIGN_OFF;   // doubles as simT scratch before align_kernel
    float* dpred = out + DPRED_OFF;

    norm_kernel<<<(BATCH * TL + BATCH * TS) / 4, 256, 0, stream>>>(lip, phon, lip_scale, text_scale);
    prep_kernel<<<BATCH, 512, 0, stream>>>(d_tg, lip_l, begins, ends, cof_arr);
    gemm_kernel<<<dim3(TL / 128, TS / 128, BATCH), 256, 0, stream>>>(lip, phon, lip_scale, text_scale,
                                                                     begins, ends, sim, gt, aln);
    dp_kernel<<<BATCH, 64, 0, stream>>>(aln, src_l, lip_l, cof_arr, mean_cof, start2, end2);
    align_kernel<<<dim3(TS, BATCH), 256, 0, stream>>>(start2, end2, mean_cof, aln, dpred);
}